// Round 1
// baseline (227.652 us; speedup 1.0000x reference)
//
#include <hip/hip_runtime.h>
#include <cstdint>
#include <cstddef>

// ---- problem constants ----
constexpr int B_    = 8;
constexpr int HKV_  = 8;
constexpr int G_    = 2;      // query heads per kv head
constexpr int D_    = 128;
constexpr int HID_  = 2048;
constexpr int VOCAB_= 32000;
constexpr int BS_   = 16;
constexpr int MAXB_ = 256;
constexpr int L_    = 4096;

// ---- tiling ----
constexpr int KSP_QKV = 16;  constexpr int CK_QKV = HID_ / KSP_QKV;   // 128
constexpr int KSP_O   = 16;  constexpr int CK_O   = HID_ / KSP_O;     // 128
constexpr int KSP_LM  = 8;   constexpr int CK_LM  = HID_ / KSP_LM;    // 256
constexpr int CHUNK   = 512; constexpr int NCHUNK = L_ / CHUNK;       // 8
constexpr int NCOL_QKV = HID_ + HKV_*D_ + HKV_*D_;                    // 4096

// ---- workspace layout (floats) ----
constexpr size_t OFF_XF   = 0;                                  // 8*2048
constexpr size_t OFF_Q    = OFF_XF   + (size_t)B_*HID_;         // 8*2048
constexpr size_t OFF_KN   = OFF_Q    + (size_t)B_*HID_;         // 8*1024
constexpr size_t OFF_VN   = OFF_KN   + (size_t)B_*HKV_*D_;      // 8*1024
constexpr size_t OFF_PQKV = OFF_VN   + (size_t)B_*HKV_*D_;      // 16*8*4096
constexpr size_t OFF_PM   = OFF_PQKV + (size_t)KSP_QKV*B_*NCOL_QKV;
constexpr size_t OFF_PL   = OFF_PM   + (size_t)B_*HKV_*NCHUNK*G_;
constexpr size_t OFF_PACC = OFF_PL   + (size_t)B_*HKV_*NCHUNK*G_;
constexpr size_t OFF_AO   = OFF_PACC + (size_t)B_*HKV_*NCHUNK*G_*D_;
constexpr size_t OFF_Y    = OFF_AO   + (size_t)B_*HID_;
constexpr size_t OFF_PO   = OFF_Y    + (size_t)B_*HID_;
constexpr size_t OFF_PLM  = OFF_PO   + (size_t)KSP_O*B_*HID_;
// end = OFF_PLM + KSP_LM*B_*VOCAB ~= 3.05M floats ~= 12.2 MB

// ---------------- K1: embedding gather ----------------
__global__ void k_embed(const int* __restrict__ tokens, const float* __restrict__ embed,
                        float* __restrict__ xf) {
    int b = blockIdx.x;
    const float4* src = (const float4*)(embed + (size_t)tokens[b] * HID_);
    float4* dst = (float4*)(xf + (size_t)b * HID_);
    for (int i = threadIdx.x; i < HID_/4; i += blockDim.x) dst[i] = src[i];
}

// ---------------- K2: fused q/k/v projection partials ----------------
__global__ __launch_bounds__(256) void k_qkv_part(const float* __restrict__ xf,
        const float* __restrict__ Wq, const float* __restrict__ Wk,
        const float* __restrict__ Wv, float* __restrict__ pout) {
    __shared__ float xs[CK_QKV * 8];           // [kk][b]
    const int c  = blockIdx.y;
    const int k0 = c * CK_QKV;
    const int n  = blockIdx.x * 256 + threadIdx.x;   // 0..4095
    for (int idx = threadIdx.x; idx < CK_QKV*8; idx += 256) {
        int b = idx >> 7, kk = idx & (CK_QKV-1);
        xs[kk*8 + b] = xf[(size_t)b*HID_ + k0 + kk];
    }
    const float* Wp; int stride, col;
    if (n < HID_)            { Wp = Wq; stride = HID_;      col = n; }
    else if (n < HID_+1024)  { Wp = Wk; stride = HKV_*D_;   col = n - HID_; }
    else                     { Wp = Wv; stride = HKV_*D_;   col = n - HID_ - 1024; }
    __syncthreads();
    float acc[8] = {0,0,0,0,0,0,0,0};
    const float* wp = Wp + (size_t)k0 * stride + col;
    for (int kk = 0; kk < CK_QKV; ++kk) {
        float w = *wp; wp += stride;
        float4 x0 = *(const float4*)&xs[kk*8];
        float4 x1 = *(const float4*)&xs[kk*8 + 4];
        acc[0] += x0.x*w; acc[1] += x0.y*w; acc[2] += x0.z*w; acc[3] += x0.w*w;
        acc[4] += x1.x*w; acc[5] += x1.y*w; acc[6] += x1.z*w; acc[7] += x1.w*w;
    }
    float* po = pout + (size_t)c * 8 * NCOL_QKV;
    #pragma unroll
    for (int b = 0; b < 8; ++b) po[(size_t)b*NCOL_QKV + n] = acc[b];
}

// ---------------- K3: combine qkv partials ----------------
__global__ void k_qkv_comb(const float* __restrict__ pqkv, float* __restrict__ q,
                           float* __restrict__ kn, float* __restrict__ vn) {
    int id = blockIdx.x * 256 + threadIdx.x;     // 0..32767
    int b = id >> 12, n = id & (NCOL_QKV-1);
    float s = 0.f;
    #pragma unroll
    for (int c = 0; c < KSP_QKV; ++c) s += pqkv[((size_t)c*8 + b)*NCOL_QKV + n];
    if (n < HID_)            q [(size_t)b*HID_ + n]            = s;
    else if (n < HID_+1024)  kn[(size_t)b*HKV_*D_ + n - HID_]  = s;
    else                     vn[(size_t)b*HKV_*D_ + n - HID_ - 1024] = s;
}

// ---------------- K4: flash-decode attention partials ----------------
__global__ __launch_bounds__(256) void k_attn(const float* __restrict__ q,
        const float* __restrict__ kn, const float* __restrict__ vn,
        const float* __restrict__ kc, const float* __restrict__ vc,
        const int* __restrict__ positions, const int* __restrict__ btab,
        float* __restrict__ pm, float* __restrict__ pl, float* __restrict__ pacc) {
    const int ch = blockIdx.x, hkv = blockIdx.y, b = blockIdx.z;
    const int pos = positions[b];
    const int c0  = ch * CHUNK;
    const size_t pbase = (size_t)(b*HKV_ + hkv)*NCHUNK + ch;
    const int t = threadIdx.x;
    if (c0 > pos) {   // nothing valid in this chunk
        if (t < 2) { pm[pbase*2 + t] = -1e30f; pl[pbase*2 + t] = 0.f; }
        pacc[pbase*256 + t] = 0.f;
        return;
    }
    const int nv = min(CHUNK, pos + 1 - c0);

    __shared__ float s_lds[2][CHUNK];
    __shared__ float red[256];
    __shared__ float acc_l[8][256];
    __shared__ float ls_l[8][2];
    __shared__ float msh[2];

    const int hw = t >> 5, l32 = t & 31;
    const float scale = 0.08838834764831845f;   // 1/sqrt(128)
    float4 q0 = *(const float4*)&q[(size_t)b*HID_ + (hkv*G_+0)*D_ + l32*4];
    float4 q1 = *(const float4*)&q[(size_t)b*HID_ + (hkv*G_+1)*D_ + l32*4];
    q0.x*=scale; q0.y*=scale; q0.z*=scale; q0.w*=scale;
    q1.x*=scale; q1.y*=scale; q1.z*=scale; q1.w*=scale;

    // phase 1: scores -> LDS
    for (int l = c0 + hw; l < c0 + nv; l += 8) {
        float4 kv;
        if (l == pos) {
            kv = *(const float4*)&kn[(size_t)b*HKV_*D_ + hkv*D_ + l32*4];
        } else {
            size_t row = (size_t)btab[b*MAXB_ + (l >> 4)] * BS_ + (l & (BS_-1));
            kv = *(const float4*)&kc[(row*HKV_ + hkv)*D_ + l32*4];
        }
        float s0 = q0.x*kv.x + q0.y*kv.y + q0.z*kv.z + q0.w*kv.w;
        float s1 = q1.x*kv.x + q1.y*kv.y + q1.z*kv.z + q1.w*kv.w;
        #pragma unroll
        for (int m = 16; m >= 1; m >>= 1) { s0 += __shfl_xor(s0, m); s1 += __shfl_xor(s1, m); }
        if (l32 == 0) { s_lds[0][l - c0] = s0; s_lds[1][l - c0] = s1; }
    }
    __syncthreads();

    // block max per head
    {
        int g = t >> 7, i0 = t & 127;
        float mx = -1e30f;
        for (int i = i0; i < nv; i += 128) mx = fmaxf(mx, s_lds[g][i]);
        red[t] = mx; __syncthreads();
        for (int s = 64; s >= 1; s >>= 1) {
            if ((t & 127) < s) red[t] = fmaxf(red[t], red[t + s]);
            __syncthreads();
        }
        if (t == 0)   msh[0] = red[0];
        if (t == 128) msh[1] = red[128];
        __syncthreads();
    }
    const float m0 = msh[0], m1 = msh[1];

    // phase 2: exp + PV accumulate
    float a0[4] = {0,0,0,0}, a1[4] = {0,0,0,0};
    float l0 = 0.f, l1 = 0.f;
    for (int l = c0 + hw; l < c0 + nv; l += 8) {
        float4 vv;
        if (l == pos) {
            vv = *(const float4*)&vn[(size_t)b*HKV_*D_ + hkv*D_ + l32*4];
        } else {
            size_t row = (size_t)btab[b*MAXB_ + (l >> 4)] * BS_ + (l & (BS_-1));
            vv = *(const float4*)&vc[(row*HKV_ + hkv)*D_ + l32*4];
        }
        float p0 = __expf(s_lds[0][l - c0] - m0);
        float p1 = __expf(s_lds[1][l - c0] - m1);
        l0 += p0; l1 += p1;
        a0[0] += p0*vv.x; a0[1] += p0*vv.y; a0[2] += p0*vv.z; a0[3] += p0*vv.w;
        a1[0] += p1*vv.x; a1[1] += p1*vv.y; a1[2] += p1*vv.z; a1[3] += p1*vv.w;
    }
    *(float4*)&acc_l[hw][0*D_ + l32*4] = make_float4(a0[0],a0[1],a0[2],a0[3]);
    *(float4*)&acc_l[hw][1*D_ + l32*4] = make_float4(a1[0],a1[1],a1[2],a1[3]);
    if (l32 == 0) { ls_l[hw][0] = l0; ls_l[hw][1] = l1; }
    __syncthreads();

    {
        float s = 0.f;
        #pragma unroll
        for (int h2 = 0; h2 < 8; ++h2) s += acc_l[h2][t];
        pacc[pbase*256 + t] = s;
    }
    if (t < 2) {
        float s = 0.f;
        #pragma unroll
        for (int h2 = 0; h2 < 8; ++h2) s += ls_l[h2][t];
        pl[pbase*2 + t] = s;
        pm[pbase*2 + t] = msh[t];
    }
}

// ---------------- K5: combine attention partials ----------------
__global__ void k_attn_comb(const float* __restrict__ pm, const float* __restrict__ pl,
                            const float* __restrict__ pacc, float* __restrict__ ao) {
    const int bh = blockIdx.x;          // b*8 + hkv
    const int t = threadIdx.x;          // 256 = 2 heads * 128 dims
    const int g = t >> 7, d = t & 127;
    const size_t base = (size_t)bh * NCHUNK;
    float M = -1e30f;
    #pragma unroll
    for (int c = 0; c < NCHUNK; ++c) M = fmaxf(M, pm[(base+c)*2 + g]);
    float Ls = 0.f, val = 0.f;
    #pragma unroll
    for (int c = 0; c < NCHUNK; ++c) {
        float w = __expf(pm[(base+c)*2 + g] - M);
        Ls  += w * pl[(base+c)*2 + g];
        val += w * pacc[(base+c)*256 + g*D_ + d];
    }
    int b = bh >> 3, hkv = bh & 7;
    ao[(size_t)b*HID_ + (hkv*G_+g)*D_ + d] = val / Ls;
}

// ---------------- K6: o_proj partials ----------------
__global__ __launch_bounds__(256) void k_o_part(const float* __restrict__ ao,
        const float* __restrict__ Wo, float* __restrict__ po) {
    __shared__ float xs[CK_O * 8];
    const int c  = blockIdx.y;
    const int k0 = c * CK_O;
    const int n  = blockIdx.x * 256 + threadIdx.x;  // 0..2047
    for (int idx = threadIdx.x; idx < CK_O*8; idx += 256) {
        int b = idx >> 7, kk = idx & (CK_O-1);
        xs[kk*8 + b] = ao[(size_t)b*HID_ + k0 + kk];
    }
    __syncthreads();
    float acc[8] = {0,0,0,0,0,0,0,0};
    const float* wp = Wo + (size_t)k0 * HID_ + n;
    for (int kk = 0; kk < CK_O; ++kk) {
        float w = *wp; wp += HID_;
        float4 x0 = *(const float4*)&xs[kk*8];
        float4 x1 = *(const float4*)&xs[kk*8 + 4];
        acc[0] += x0.x*w; acc[1] += x0.y*w; acc[2] += x0.z*w; acc[3] += x0.w*w;
        acc[4] += x1.x*w; acc[5] += x1.y*w; acc[6] += x1.z*w; acc[7] += x1.w*w;
    }
    #pragma unroll
    for (int b = 0; b < 8; ++b) po[((size_t)c*8 + b)*HID_ + n] = acc[b];
}

// ---------------- K7: residual add ----------------
__global__ void k_resid(const float* __restrict__ xf, const float* __restrict__ po,
                        float* __restrict__ y) {
    int id = blockIdx.x * 256 + threadIdx.x;  // 0..16383
    int b = id >> 11, n = id & (HID_-1);
    float s = xf[id];
    #pragma unroll
    for (int c = 0; c < KSP_O; ++c) s += po[((size_t)c*8 + b)*HID_ + n];
    y[id] = s;
}

// ---------------- K8: lm_head partials ----------------
__global__ __launch_bounds__(256) void k_lm_part(const float* __restrict__ y,
        const float* __restrict__ Wlm, float* __restrict__ plm) {
    __shared__ float xs[CK_LM * 8];  // 8 KB, [kk][b]
    const int c  = blockIdx.y;
    const int k0 = c * CK_LM;
    const int n  = blockIdx.x * 256 + threadIdx.x;  // 0..31999
    for (int idx = threadIdx.x; idx < CK_LM*8; idx += 256) {
        int b = idx >> 8, kk = idx & (CK_LM-1);
        xs[kk*8 + b] = y[(size_t)b*HID_ + k0 + kk];
    }
    __syncthreads();
    float acc[8] = {0,0,0,0,0,0,0,0};
    const float* wp = Wlm + (size_t)k0 * VOCAB_ + n;
    for (int kk = 0; kk < CK_LM; ++kk) {
        float w = *wp; wp += VOCAB_;
        float4 x0 = *(const float4*)&xs[kk*8];
        float4 x1 = *(const float4*)&xs[kk*8 + 4];
        acc[0] += x0.x*w; acc[1] += x0.y*w; acc[2] += x0.z*w; acc[3] += x0.w*w;
        acc[4] += x1.x*w; acc[5] += x1.y*w; acc[6] += x1.z*w; acc[7] += x1.w*w;
    }
    #pragma unroll
    for (int b = 0; b < 8; ++b) plm[((size_t)c*8 + b)*VOCAB_ + n] = acc[b];
}

// ---------------- K9: lm_head combine -> logits ----------------
__global__ void k_lm_comb(const float* __restrict__ plm, float* __restrict__ out) {
    int n = blockIdx.x * 256 + threadIdx.x;   // 0..31999
    #pragma unroll
    for (int b = 0; b < 8; ++b) {
        float s = 0.f;
        #pragma unroll
        for (int c = 0; c < KSP_LM; ++c) s += plm[((size_t)c*8 + b)*VOCAB_ + n];
        out[(size_t)b*VOCAB_ + n] = s;
    }
}

extern "C" void kernel_launch(void* const* d_in, const int* in_sizes, int n_in,
                              void* d_out, int out_size, void* d_ws, size_t ws_size,
                              hipStream_t stream) {
    const int*   tokens    = (const int*)  d_in[0];
    const int*   positions = (const int*)  d_in[1];
    const int*   btab      = (const int*)  d_in[2];
    const float* kc        = (const float*)d_in[3];
    const float* vc        = (const float*)d_in[4];
    const float* embed     = (const float*)d_in[5];
    const float* Wq        = (const float*)d_in[6];
    const float* Wk        = (const float*)d_in[7];
    const float* Wv        = (const float*)d_in[8];
    const float* Wo        = (const float*)d_in[9];
    const float* Wlm       = (const float*)d_in[10];
    float* out = (float*)d_out;
    float* ws  = (float*)d_ws;

    float* xf   = ws + OFF_XF;
    float* q    = ws + OFF_Q;
    float* kn   = ws + OFF_KN;
    float* vn   = ws + OFF_VN;
    float* pqkv = ws + OFF_PQKV;
    float* pm   = ws + OFF_PM;
    float* pl   = ws + OFF_PL;
    float* pacc = ws + OFF_PACC;
    float* ao   = ws + OFF_AO;
    float* y    = ws + OFF_Y;
    float* po   = ws + OFF_PO;
    float* plm  = ws + OFF_PLM;

    k_embed   <<<B_, 256, 0, stream>>>(tokens, embed, xf);
    k_qkv_part<<<dim3(NCOL_QKV/256, KSP_QKV), 256, 0, stream>>>(xf, Wq, Wk, Wv, pqkv);
    k_qkv_comb<<<(B_*NCOL_QKV)/256, 256, 0, stream>>>(pqkv, q, kn, vn);
    k_attn    <<<dim3(NCHUNK, HKV_, B_), 256, 0, stream>>>(q, kn, vn, kc, vc,
                                                           positions, btab, pm, pl, pacc);
    k_attn_comb<<<B_*HKV_, 256, 0, stream>>>(pm, pl, pacc, ao);
    k_o_part  <<<dim3(HID_/256, KSP_O), 256, 0, stream>>>(ao, Wo, po);
    k_resid   <<<(B_*HID_)/256, 256, 0, stream>>>(xf, po, y);
    k_lm_part <<<dim3(VOCAB_/256, KSP_LM), 256, 0, stream>>>(y, Wlm, plm);
    k_lm_comb <<<VOCAB_/256, 256, 0, stream>>>(plm, out);
}

// Round 2
// 141.080 us; speedup vs baseline: 1.6136x; 1.6136x over previous
//
#include <hip/hip_runtime.h>
#include <cstdint>
#include <cstddef>

// ---- problem constants ----
constexpr int B_    = 8;
constexpr int HKV_  = 8;
constexpr int G_    = 2;      // query heads per kv head
constexpr int D_    = 128;
constexpr int HID_  = 2048;
constexpr int VOCAB_= 32000;
constexpr int BS_   = 16;
constexpr int MAXB_ = 256;
constexpr int L_    = 4096;

// ---- tiling ----
constexpr int KSP_QKV = 16;  constexpr int CK_QKV = HID_ / KSP_QKV;   // 128
constexpr int KSP_O   = 16;  constexpr int CK_O   = HID_ / KSP_O;     // 128
constexpr int KSP_LM  = 8;   constexpr int CK_LM  = HID_ / KSP_LM;    // 256
constexpr int CHUNK   = 128; constexpr int NCHUNK = L_ / CHUNK;       // 32
constexpr int NCOL_QKV = HID_ + HKV_*D_ + HKV_*D_;                    // 4096

// ---- workspace layout (floats) ----
constexpr size_t OFF_Q    = 0;                                  // 8*2048
constexpr size_t OFF_KN   = OFF_Q    + (size_t)B_*HID_;         // 8*1024
constexpr size_t OFF_VN   = OFF_KN   + (size_t)B_*HKV_*D_;      // 8*1024
constexpr size_t OFF_PQKV = OFF_VN   + (size_t)B_*HKV_*D_;      // 16*8*4096
constexpr size_t OFF_PM   = OFF_PQKV + (size_t)KSP_QKV*B_*NCOL_QKV;
constexpr size_t OFF_PL   = OFF_PM   + (size_t)B_*HKV_*NCHUNK*G_;
constexpr size_t OFF_PACC = OFF_PL   + (size_t)B_*HKV_*NCHUNK*G_;
constexpr size_t OFF_AO   = OFF_PACC + (size_t)B_*HKV_*NCHUNK*G_*D_;
constexpr size_t OFF_Y    = OFF_AO   + (size_t)B_*HID_;
constexpr size_t OFF_PO   = OFF_Y    + (size_t)B_*HID_;
constexpr size_t OFF_PLM  = OFF_PO   + (size_t)KSP_O*B_*HID_;
// end = OFF_PLM + KSP_LM*B_*VOCAB ~= 3.4M floats ~= 13.7 MB

// ---------------- K2: fused q/k/v projection partials (reads embed directly) ----
__global__ __launch_bounds__(256) void k_qkv_part(const int* __restrict__ tokens,
        const float* __restrict__ embed,
        const float* __restrict__ Wq, const float* __restrict__ Wk,
        const float* __restrict__ Wv, float* __restrict__ pout) {
    __shared__ float xs[CK_QKV * 8];           // [kk][b]
    const int c  = blockIdx.y;
    const int k0 = c * CK_QKV;
    const int n  = blockIdx.x * 256 + threadIdx.x;   // 0..4095
    for (int idx = threadIdx.x; idx < CK_QKV*8; idx += 256) {
        int b = idx >> 7, kk = idx & (CK_QKV-1);
        xs[kk*8 + b] = embed[(size_t)tokens[b]*HID_ + k0 + kk];
    }
    const float* Wp; int stride, col;
    if (n < HID_)            { Wp = Wq; stride = HID_;      col = n; }
    else if (n < HID_+1024)  { Wp = Wk; stride = HKV_*D_;   col = n - HID_; }
    else                     { Wp = Wv; stride = HKV_*D_;   col = n - HID_ - 1024; }
    __syncthreads();
    float acc[8] = {0,0,0,0,0,0,0,0};
    const float* wp = Wp + (size_t)k0 * stride + col;
    for (int kk = 0; kk < CK_QKV; ++kk) {
        float w = *wp; wp += stride;
        float4 x0 = *(const float4*)&xs[kk*8];
        float4 x1 = *(const float4*)&xs[kk*8 + 4];
        acc[0] += x0.x*w; acc[1] += x0.y*w; acc[2] += x0.z*w; acc[3] += x0.w*w;
        acc[4] += x1.x*w; acc[5] += x1.y*w; acc[6] += x1.z*w; acc[7] += x1.w*w;
    }
    float* po = pout + (size_t)c * 8 * NCOL_QKV;
    #pragma unroll
    for (int b = 0; b < 8; ++b) po[(size_t)b*NCOL_QKV + n] = acc[b];
}

// ---------------- K3: combine qkv partials ----------------
__global__ void k_qkv_comb(const float* __restrict__ pqkv, float* __restrict__ q,
                           float* __restrict__ kn, float* __restrict__ vn) {
    int id = blockIdx.x * 256 + threadIdx.x;     // 0..32767
    int b = id >> 12, n = id & (NCOL_QKV-1);
    float s = 0.f;
    #pragma unroll
    for (int c = 0; c < KSP_QKV; ++c) s += pqkv[((size_t)c*8 + b)*NCOL_QKV + n];
    if (n < HID_)            q [(size_t)b*HID_ + n]            = s;
    else if (n < HID_+1024)  kn[(size_t)b*HKV_*D_ + n - HID_]  = s;
    else                     vn[(size_t)b*HKV_*D_ + n - HID_ - 1024] = s;
}

// ---------------- K4: flash-decode attention partials (fused K+V, online softmax) ----
__global__ __launch_bounds__(256) void k_attn(const float* __restrict__ q,
        const float* __restrict__ kn, const float* __restrict__ vn,
        const float* __restrict__ kc, const float* __restrict__ vc,
        const int* __restrict__ positions, const int* __restrict__ btab,
        float* __restrict__ pm, float* __restrict__ pl, float* __restrict__ pacc) {
    const int ch = blockIdx.x, hkv = blockIdx.y, b = blockIdx.z;
    const int pos = positions[b];
    const int c0  = ch * CHUNK;
    const size_t pbase = (size_t)(b*HKV_ + hkv)*NCHUNK + ch;
    const int t = threadIdx.x;
    if (c0 > pos) {   // nothing valid in this chunk
        if (t < 2) { pm[pbase*2 + t] = -1e30f; pl[pbase*2 + t] = 0.f; }
        pacc[pbase*256 + t] = 0.f;
        return;
    }
    const int hw = t >> 5, l32 = t & 31;
    const float scale = 0.08838834764831845f;   // 1/sqrt(128)
    float4 q0 = *(const float4*)&q[(size_t)b*HID_ + (hkv*G_+0)*D_ + l32*4];
    float4 q1 = *(const float4*)&q[(size_t)b*HID_ + (hkv*G_+1)*D_ + l32*4];
    q0.x*=scale; q0.y*=scale; q0.z*=scale; q0.w*=scale;
    q1.x*=scale; q1.y*=scale; q1.z*=scale; q1.w*=scale;

    float m0 = -1e30f, m1 = -1e30f, l0 = 0.f, l1 = 0.f;
    float a0[4] = {0,0,0,0}, a1[4] = {0,0,0,0};
    const int* bt = btab + b * MAXB_;
    const size_t knoff = ((size_t)b*HKV_ + hkv)*D_ + l32*4;

    #pragma unroll 4
    for (int i = 0; i < CHUNK/8; ++i) {
        const int l = c0 + hw + i*8;                 // uniform per half-wave
        const bool valid = (l <= pos);
        const float *kp, *vp;
        if (l == pos) {
            kp = kn + knoff;  vp = vn + knoff;
        } else {
            size_t row = (size_t)bt[l >> 4] * BS_ + (l & (BS_-1));
            size_t off = (row*HKV_ + hkv)*D_ + l32*4;
            kp = kc + off;    vp = vc + off;
        }
        float4 kv = *(const float4*)kp;
        float4 vv = *(const float4*)vp;
        float s0 = q0.x*kv.x + q0.y*kv.y + q0.z*kv.z + q0.w*kv.w;
        float s1 = q1.x*kv.x + q1.y*kv.y + q1.z*kv.z + q1.w*kv.w;
        #pragma unroll
        for (int m = 16; m >= 1; m >>= 1) { s0 += __shfl_xor(s0, m); s1 += __shfl_xor(s1, m); }
        if (!valid) { s0 = -1e30f; s1 = -1e30f; }
        // online softmax update, head g=0
        float nm0 = fmaxf(m0, s0);
        float cr0 = __expf(m0 - nm0);
        float p0  = valid ? __expf(s0 - nm0) : 0.f;
        m0 = nm0; l0 = l0*cr0 + p0;
        a0[0] = a0[0]*cr0 + p0*vv.x; a0[1] = a0[1]*cr0 + p0*vv.y;
        a0[2] = a0[2]*cr0 + p0*vv.z; a0[3] = a0[3]*cr0 + p0*vv.w;
        // head g=1
        float nm1 = fmaxf(m1, s1);
        float cr1 = __expf(m1 - nm1);
        float p1  = valid ? __expf(s1 - nm1) : 0.f;
        m1 = nm1; l1 = l1*cr1 + p1;
        a1[0] = a1[0]*cr1 + p1*vv.x; a1[1] = a1[1]*cr1 + p1*vv.y;
        a1[2] = a1[2]*cr1 + p1*vv.z; a1[3] = a1[3]*cr1 + p1*vv.w;
    }

    // combine 8 half-wave online states -> block partial
    __shared__ float acc_l[8][256];
    __shared__ float ml_l[8][2][2];   // [hw][g][{m,l}]
    *(float4*)&acc_l[hw][0*D_ + l32*4] = make_float4(a0[0],a0[1],a0[2],a0[3]);
    *(float4*)&acc_l[hw][1*D_ + l32*4] = make_float4(a1[0],a1[1],a1[2],a1[3]);
    if (l32 == 0) {
        ml_l[hw][0][0] = m0; ml_l[hw][0][1] = l0;
        ml_l[hw][1][0] = m1; ml_l[hw][1][1] = l1;
    }
    __syncthreads();

    const int g = t >> 7, d = t & 127;
    float M = -1e30f;
    #pragma unroll
    for (int h = 0; h < 8; ++h) M = fmaxf(M, ml_l[h][g][0]);
    float Ls = 0.f, val = 0.f;
    #pragma unroll
    for (int h = 0; h < 8; ++h) {
        float w = __expf(ml_l[h][g][0] - M);
        Ls  += w * ml_l[h][g][1];
        val += w * acc_l[h][g*D_ + d];
    }
    pacc[pbase*256 + t] = val;
    if (d == 0) { pm[pbase*2 + g] = M; pl[pbase*2 + g] = Ls; }
}

// ---------------- K5: combine attention partials ----------------
__global__ void k_attn_comb(const float* __restrict__ pm, const float* __restrict__ pl,
                            const float* __restrict__ pacc, float* __restrict__ ao) {
    const int bh = blockIdx.x;          // b*8 + hkv
    const int t = threadIdx.x;          // 256 = 2 heads * 128 dims
    const int g = t >> 7, d = t & 127;
    const size_t base = (size_t)bh * NCHUNK;
    float M = -1e30f;
    #pragma unroll
    for (int c = 0; c < NCHUNK; ++c) M = fmaxf(M, pm[(base+c)*2 + g]);
    float Ls = 0.f, val = 0.f;
    #pragma unroll
    for (int c = 0; c < NCHUNK; ++c) {
        float w = __expf(pm[(base+c)*2 + g] - M);
        Ls  += w * pl[(base+c)*2 + g];
        val += w * pacc[(base+c)*256 + g*D_ + d];
    }
    int b = bh >> 3, hkv = bh & 7;
    ao[(size_t)b*HID_ + (hkv*G_+g)*D_ + d] = val / Ls;
}

// ---------------- K6: o_proj partials ----------------
__global__ __launch_bounds__(256) void k_o_part(const float* __restrict__ ao,
        const float* __restrict__ Wo, float* __restrict__ po) {
    __shared__ float xs[CK_O * 8];
    const int c  = blockIdx.y;
    const int k0 = c * CK_O;
    const int n  = blockIdx.x * 256 + threadIdx.x;  // 0..2047
    for (int idx = threadIdx.x; idx < CK_O*8; idx += 256) {
        int b = idx >> 7, kk = idx & (CK_O-1);
        xs[kk*8 + b] = ao[(size_t)b*HID_ + k0 + kk];
    }
    __syncthreads();
    float acc[8] = {0,0,0,0,0,0,0,0};
    const float* wp = Wo + (size_t)k0 * HID_ + n;
    for (int kk = 0; kk < CK_O; ++kk) {
        float w = *wp; wp += HID_;
        float4 x0 = *(const float4*)&xs[kk*8];
        float4 x1 = *(const float4*)&xs[kk*8 + 4];
        acc[0] += x0.x*w; acc[1] += x0.y*w; acc[2] += x0.z*w; acc[3] += x0.w*w;
        acc[4] += x1.x*w; acc[5] += x1.y*w; acc[6] += x1.z*w; acc[7] += x1.w*w;
    }
    #pragma unroll
    for (int b = 0; b < 8; ++b) po[((size_t)c*8 + b)*HID_ + n] = acc[b];
}

// ---------------- K7: residual add (reads embed directly) ----------------
__global__ void k_resid(const int* __restrict__ tokens, const float* __restrict__ embed,
                        const float* __restrict__ po, float* __restrict__ y) {
    int id = blockIdx.x * 256 + threadIdx.x;  // 0..16383
    int b = id >> 11, n = id & (HID_-1);
    float s = embed[(size_t)tokens[b]*HID_ + n];
    #pragma unroll
    for (int c = 0; c < KSP_O; ++c) s += po[((size_t)c*8 + b)*HID_ + n];
    y[id] = s;
}

// ---------------- K8: lm_head partials ----------------
__global__ __launch_bounds__(256) void k_lm_part(const float* __restrict__ y,
        const float* __restrict__ Wlm, float* __restrict__ plm) {
    __shared__ float xs[CK_LM * 8];  // 8 KB, [kk][b]
    const int c  = blockIdx.y;
    const int k0 = c * CK_LM;
    const int n  = blockIdx.x * 256 + threadIdx.x;  // 0..31999
    for (int idx = threadIdx.x; idx < CK_LM*8; idx += 256) {
        int b = idx >> 8, kk = idx & (CK_LM-1);
        xs[kk*8 + b] = y[(size_t)b*HID_ + k0 + kk];
    }
    __syncthreads();
    float acc[8] = {0,0,0,0,0,0,0,0};
    const float* wp = Wlm + (size_t)k0 * VOCAB_ + n;
    for (int kk = 0; kk < CK_LM; ++kk) {
        float w = *wp; wp += VOCAB_;
        float4 x0 = *(const float4*)&xs[kk*8];
        float4 x1 = *(const float4*)&xs[kk*8 + 4];
        acc[0] += x0.x*w; acc[1] += x0.y*w; acc[2] += x0.z*w; acc[3] += x0.w*w;
        acc[4] += x1.x*w; acc[5] += x1.y*w; acc[6] += x1.z*w; acc[7] += x1.w*w;
    }
    #pragma unroll
    for (int b = 0; b < 8; ++b) plm[((size_t)c*8 + b)*VOCAB_ + n] = acc[b];
}

// ---------------- K9: lm_head combine -> logits ----------------
__global__ void k_lm_comb(const float* __restrict__ plm, float* __restrict__ out) {
    int n = blockIdx.x * 256 + threadIdx.x;   // 0..31999
    #pragma unroll
    for (int b = 0; b < 8; ++b) {
        float s = 0.f;
        #pragma unroll
        for (int c = 0; c < KSP_LM; ++c) s += plm[((size_t)c*8 + b)*VOCAB_ + n];
        out[(size_t)b*VOCAB_ + n] = s;
    }
}

extern "C" void kernel_launch(void* const* d_in, const int* in_sizes, int n_in,
                              void* d_out, int out_size, void* d_ws, size_t ws_size,
                              hipStream_t stream) {
    const int*   tokens    = (const int*)  d_in[0];
    const int*   positions = (const int*)  d_in[1];
    const int*   btab      = (const int*)  d_in[2];
    const float* kc        = (const float*)d_in[3];
    const float* vc        = (const float*)d_in[4];
    const float* embed     = (const float*)d_in[5];
    const float* Wq        = (const float*)d_in[6];
    const float* Wk        = (const float*)d_in[7];
    const float* Wv        = (const float*)d_in[8];
    const float* Wo        = (const float*)d_in[9];
    const float* Wlm       = (const float*)d_in[10];
    float* out = (float*)d_out;
    float* ws  = (float*)d_ws;

    float* q    = ws + OFF_Q;
    float* kn   = ws + OFF_KN;
    float* vn   = ws + OFF_VN;
    float* pqkv = ws + OFF_PQKV;
    float* pm   = ws + OFF_PM;
    float* pl   = ws + OFF_PL;
    float* pacc = ws + OFF_PACC;
    float* ao   = ws + OFF_AO;
    float* y    = ws + OFF_Y;
    float* po   = ws + OFF_PO;
    float* plm  = ws + OFF_PLM;

    k_qkv_part<<<dim3(NCOL_QKV/256, KSP_QKV), 256, 0, stream>>>(tokens, embed, Wq, Wk, Wv, pqkv);
    k_qkv_comb<<<(B_*NCOL_QKV)/256, 256, 0, stream>>>(pqkv, q, kn, vn);
    k_attn    <<<dim3(NCHUNK, HKV_, B_), 256, 0, stream>>>(q, kn, vn, kc, vc,
                                                           positions, btab, pm, pl, pacc);
    k_attn_comb<<<B_*HKV_, 256, 0, stream>>>(pm, pl, pacc, ao);
    k_o_part  <<<dim3(HID_/256, KSP_O), 256, 0, stream>>>(ao, Wo, po);
    k_resid   <<<(B_*HID_)/256, 256, 0, stream>>>(tokens, embed, po, y);
    k_lm_part <<<dim3(VOCAB_/256, KSP_LM), 256, 0, stream>>>(y, Wlm, plm);
    k_lm_comb <<<VOCAB_/256, 256, 0, stream>>>(plm, out);
}

// Round 3
// 125.723 us; speedup vs baseline: 1.8107x; 1.1222x over previous
//
#include <hip/hip_runtime.h>
#include <cstdint>
#include <cstddef>

// ---- problem constants ----
constexpr int B_    = 8;
constexpr int HKV_  = 8;
constexpr int G_    = 2;      // query heads per kv head
constexpr int D_    = 128;
constexpr int HID_  = 2048;
constexpr int VOCAB_= 32000;
constexpr int BS_   = 16;
constexpr int MAXB_ = 256;
constexpr int L_    = 4096;

// ---- tiling ----
constexpr int KSP_QKV = 32;  constexpr int CK_QKV = HID_ / KSP_QKV;  // 64
constexpr int KSP_O   = 32;                                          // 64 K-rows each
constexpr int KSP_LM  = 16;  constexpr int CK_LM  = HID_ / KSP_LM;   // 128
constexpr int CHUNK   = 128; constexpr int NCHUNK = L_ / CHUNK;      // 32
constexpr int NCOL_QKV = HID_ + 1024 + 1024;                         // 4096

// ---- workspace layout (floats) ----
constexpr size_t OFF_PQKV = 0;                                         // 32*8*4096
constexpr size_t OFF_PM   = OFF_PQKV + (size_t)KSP_QKV*B_*NCOL_QKV;
constexpr size_t OFF_PL   = OFF_PM   + (size_t)B_*HKV_*NCHUNK*G_;
constexpr size_t OFF_PACC = OFF_PL   + (size_t)B_*HKV_*NCHUNK*G_;
constexpr size_t OFF_PO   = OFF_PACC + (size_t)B_*HKV_*NCHUNK*G_*D_;
constexpr size_t OFF_PLM  = OFF_PO   + (size_t)KSP_O*B_*HID_;
// end = OFF_PLM + 16*8*32000 ~= 6.2M floats ~= 25 MB

// ---------------- K1: fused q/k/v projection partials ----------------
__global__ __launch_bounds__(256) void k_qkv_part(const int* __restrict__ tokens,
        const float* __restrict__ embed,
        const float* __restrict__ Wq, const float* __restrict__ Wk,
        const float* __restrict__ Wv, float* __restrict__ pout) {
    __shared__ float xs[CK_QKV * 8];           // [kk][b]
    const int c  = blockIdx.y;
    const int k0 = c * CK_QKV;
    const int n  = blockIdx.x * 256 + threadIdx.x;   // 0..4095
    for (int idx = threadIdx.x; idx < CK_QKV*8; idx += 256) {
        int b = idx >> 6, kk = idx & (CK_QKV-1);
        xs[kk*8 + b] = embed[(size_t)tokens[b]*HID_ + k0 + kk];
    }
    const float* Wp; int stride, col;
    if (n < HID_)            { Wp = Wq; stride = HID_; col = n; }
    else if (n < HID_+1024)  { Wp = Wk; stride = 1024; col = n - HID_; }
    else                     { Wp = Wv; stride = 1024; col = n - HID_ - 1024; }
    __syncthreads();
    float acc[8] = {0,0,0,0,0,0,0,0};
    const float* wp = Wp + (size_t)k0 * stride + col;
    #pragma unroll 8
    for (int kk = 0; kk < CK_QKV; ++kk) {
        float w = *wp; wp += stride;
        float4 x0 = *(const float4*)&xs[kk*8];
        float4 x1 = *(const float4*)&xs[kk*8 + 4];
        acc[0] += x0.x*w; acc[1] += x0.y*w; acc[2] += x0.z*w; acc[3] += x0.w*w;
        acc[4] += x1.x*w; acc[5] += x1.y*w; acc[6] += x1.z*w; acc[7] += x1.w*w;
    }
    float* po = pout + (size_t)c * 8 * NCOL_QKV + n;
    #pragma unroll
    for (int b = 0; b < 8; ++b) po[(size_t)b*NCOL_QKV] = acc[b];
}

// ---------------- K2: flash-decode attention (inline qkv combine) ----------------
__global__ __launch_bounds__(256) void k_attn(const float* __restrict__ pqkv,
        const float* __restrict__ kc, const float* __restrict__ vc,
        const int* __restrict__ positions, const int* __restrict__ btab,
        float* __restrict__ pm, float* __restrict__ pl, float* __restrict__ pacc) {
    const int ch = blockIdx.x, hkv = blockIdx.y, b = blockIdx.z;
    const int pos = positions[b];
    const int c0  = ch * CHUNK;
    const size_t pbase = (size_t)(b*HKV_ + hkv)*NCHUNK + ch;
    const int t = threadIdx.x;
    if (c0 > pos) {
        if (t < 2) { pm[pbase*2 + t] = -1e30f; pl[pbase*2 + t] = 0.f; }
        pacc[pbase*256 + t] = 0.f;
        return;
    }
    const bool haspos = (pos < c0 + CHUNK);   // c0 <= pos already

    __shared__ float qs[2*D_];      // combined+scaled q, [g][d]
    __shared__ float knvs[2*D_];    // combined kn|vn row for l==pos
    __shared__ int   bts[CHUNK/BS_];
    __shared__ float acc_l[8][256];
    __shared__ float ml_l[8][2][2];

    const float4* pq4 = (const float4*)pqkv;
    const float scale = 0.08838834764831845f;   // 1/sqrt(128)
    if (t < 64) {                   // q combine: 64 float4 = 256 floats
        float4 s = make_float4(0.f,0.f,0.f,0.f);
        size_t cb4 = (size_t)hkv*64 + t;        // (hkv*256)/4 + t
        for (int cc = 0; cc < KSP_QKV; ++cc) {
            float4 p = pq4[(size_t)(cc*8 + b)*(NCOL_QKV/4) + cb4];
            s.x += p.x; s.y += p.y; s.z += p.z; s.w += p.w;
        }
        s.x *= scale; s.y *= scale; s.z *= scale; s.w *= scale;
        ((float4*)qs)[t] = s;
    } else if (t < 128 && haspos) { // kn|vn combine: 64 float4
        int j = t - 64;
        size_t cb4 = (j < 32) ? (size_t)(HID_ + hkv*D_)/4 + j
                              : (size_t)(HID_ + 1024 + hkv*D_)/4 + (j - 32);
        float4 s = make_float4(0.f,0.f,0.f,0.f);
        for (int cc = 0; cc < KSP_QKV; ++cc) {
            float4 p = pq4[(size_t)(cc*8 + b)*(NCOL_QKV/4) + cb4];
            s.x += p.x; s.y += p.y; s.z += p.z; s.w += p.w;
        }
        ((float4*)knvs)[j] = s;
    }
    if (t < CHUNK/BS_) bts[t] = btab[b*MAXB_ + ch*(CHUNK/BS_) + t];
    __syncthreads();

    const int hw = t >> 5, l32 = t & 31;
    float4 q0 = ((const float4*)qs)[l32];
    float4 q1 = ((const float4*)qs)[32 + l32];

    float m0 = -1e30f, m1 = -1e30f, l0 = 0.f, l1 = 0.f;
    float a0[4] = {0,0,0,0}, a1[4] = {0,0,0,0};

    #pragma unroll 8
    for (int i = 0; i < CHUNK/8; ++i) {
        const int lo = i*8 + hw;                 // offset in chunk, uniform per half-wave
        const int l  = c0 + lo;
        const bool valid = (l < pos);            // l==pos handled separately
        size_t row = (size_t)bts[lo >> 4] * BS_ + (lo & (BS_-1));
        size_t off = (row*HKV_ + hkv)*D_ + l32*4;
        float4 kv = *(const float4*)(kc + off);
        float4 vv = *(const float4*)(vc + off);
        float s0 = q0.x*kv.x + q0.y*kv.y + q0.z*kv.z + q0.w*kv.w;
        float s1 = q1.x*kv.x + q1.y*kv.y + q1.z*kv.z + q1.w*kv.w;
        #pragma unroll
        for (int m = 16; m >= 1; m >>= 1) { s0 += __shfl_xor(s0, m); s1 += __shfl_xor(s1, m); }
        if (!valid) { s0 = -1e30f; s1 = -1e30f; }
        float nm0 = fmaxf(m0, s0);
        float cr0 = __expf(m0 - nm0);
        float p0  = valid ? __expf(s0 - nm0) : 0.f;
        m0 = nm0; l0 = l0*cr0 + p0;
        a0[0] = a0[0]*cr0 + p0*vv.x; a0[1] = a0[1]*cr0 + p0*vv.y;
        a0[2] = a0[2]*cr0 + p0*vv.z; a0[3] = a0[3]*cr0 + p0*vv.w;
        float nm1 = fmaxf(m1, s1);
        float cr1 = __expf(m1 - nm1);
        float p1  = valid ? __expf(s1 - nm1) : 0.f;
        m1 = nm1; l1 = l1*cr1 + p1;
        a1[0] = a1[0]*cr1 + p1*vv.x; a1[1] = a1[1]*cr1 + p1*vv.y;
        a1[2] = a1[2]*cr1 + p1*vv.z; a1[3] = a1[3]*cr1 + p1*vv.w;
    }

    // new-token update (cache value at slot is stale; use combined kn/vn)
    if (haspos && hw == 0) {
        float4 kv = ((const float4*)knvs)[l32];
        float4 vv = ((const float4*)knvs)[32 + l32];
        float s0 = q0.x*kv.x + q0.y*kv.y + q0.z*kv.z + q0.w*kv.w;
        float s1 = q1.x*kv.x + q1.y*kv.y + q1.z*kv.z + q1.w*kv.w;
        #pragma unroll
        for (int m = 16; m >= 1; m >>= 1) { s0 += __shfl_xor(s0, m); s1 += __shfl_xor(s1, m); }
        float nm0 = fmaxf(m0, s0);
        float cr0 = __expf(m0 - nm0);
        float p0  = __expf(s0 - nm0);
        m0 = nm0; l0 = l0*cr0 + p0;
        a0[0] = a0[0]*cr0 + p0*vv.x; a0[1] = a0[1]*cr0 + p0*vv.y;
        a0[2] = a0[2]*cr0 + p0*vv.z; a0[3] = a0[3]*cr0 + p0*vv.w;
        float nm1 = fmaxf(m1, s1);
        float cr1 = __expf(m1 - nm1);
        float p1  = __expf(s1 - nm1);
        m1 = nm1; l1 = l1*cr1 + p1;
        a1[0] = a1[0]*cr1 + p1*vv.x; a1[1] = a1[1]*cr1 + p1*vv.y;
        a1[2] = a1[2]*cr1 + p1*vv.z; a1[3] = a1[3]*cr1 + p1*vv.w;
    }

    *(float4*)&acc_l[hw][0*D_ + l32*4] = make_float4(a0[0],a0[1],a0[2],a0[3]);
    *(float4*)&acc_l[hw][1*D_ + l32*4] = make_float4(a1[0],a1[1],a1[2],a1[3]);
    if (l32 == 0) {
        ml_l[hw][0][0] = m0; ml_l[hw][0][1] = l0;
        ml_l[hw][1][0] = m1; ml_l[hw][1][1] = l1;
    }
    __syncthreads();

    const int g = t >> 7, d = t & 127;
    float M = -1e30f;
    #pragma unroll
    for (int h = 0; h < 8; ++h) M = fmaxf(M, ml_l[h][g][0]);
    float Ls = 0.f, val = 0.f;
    #pragma unroll
    for (int h = 0; h < 8; ++h) {
        float w = __expf(ml_l[h][g][0] - M);
        Ls  += w * ml_l[h][g][1];
        val += w * acc_l[h][g*D_ + d];
    }
    pacc[pbase*256 + t] = val;
    if (d == 0) { pm[pbase*2 + g] = M; pl[pbase*2 + g] = Ls; }
}

// ---------------- K3: o_proj partials (inline attention combine) ----------------
__global__ __launch_bounds__(256) void k_o_part(const float* __restrict__ pm,
        const float* __restrict__ pl, const float* __restrict__ pacc,
        const float* __restrict__ Wo, float* __restrict__ po) {
    const int cb   = blockIdx.y;            // 0..31
    const int head = cb >> 1;               // query head 0..15
    const int hkv  = head >> 1, g = head & 1;
    const int dhalf = (cb & 1) * 64;        // which 64 dims of the head
    const int t = threadIdx.x;
    const int n = blockIdx.x * 256 + t;     // 0..2047

    __shared__ float pms[8][NCHUNK], pls[8][NCHUNK];
    __shared__ float wch[8][NCHUNK];
    __shared__ float wsum[8];
    __shared__ float xs[64 * 8];            // [kk][b]

    {   // load pm/pl for all (b, ch)
        int bb = t >> 5, ch = t & 31;
        size_t ix = ((size_t)(bb*HKV_ + hkv)*NCHUNK + ch)*2 + g;
        pms[bb][ch] = pm[ix];
        pls[bb][ch] = pl[ix];
    }
    __syncthreads();
    if (t < 8) {
        float M = -1e30f;
        for (int ch = 0; ch < NCHUNK; ++ch) M = fmaxf(M, pms[t][ch]);
        float Ls = 0.f;
        for (int ch = 0; ch < NCHUNK; ++ch) {
            float w = __expf(pms[t][ch] - M);
            wch[t][ch] = w;
            Ls += w * pls[t][ch];
        }
        wsum[t] = 1.f / Ls;
    }
    __syncthreads();
    if (t < 128) {      // stage attn-out slice [8 b][64 d] via float4
        int bb = t >> 4, j = t & 15;
        float4 a = make_float4(0.f,0.f,0.f,0.f);
        size_t base4 = ((size_t)(bb*HKV_ + hkv)*NCHUNK)*64 + (size_t)(g*128 + dhalf)/4 + j;
        for (int ch = 0; ch < NCHUNK; ++ch) {
            float w = wch[bb][ch];
            float4 p = ((const float4*)pacc)[base4 + (size_t)ch*64];
            a.x += w*p.x; a.y += w*p.y; a.z += w*p.z; a.w += w*p.w;
        }
        float inv = wsum[bb];
        xs[(j*4+0)*8 + bb] = a.x*inv;
        xs[(j*4+1)*8 + bb] = a.y*inv;
        xs[(j*4+2)*8 + bb] = a.z*inv;
        xs[(j*4+3)*8 + bb] = a.w*inv;
    }
    __syncthreads();

    float acc[8] = {0,0,0,0,0,0,0,0};
    const float* wp = Wo + (size_t)(head*D_ + dhalf) * HID_ + n;
    #pragma unroll 8
    for (int kk = 0; kk < 64; ++kk) {
        float w = *wp; wp += HID_;
        float4 x0 = *(const float4*)&xs[kk*8];
        float4 x1 = *(const float4*)&xs[kk*8 + 4];
        acc[0] += x0.x*w; acc[1] += x0.y*w; acc[2] += x0.z*w; acc[3] += x0.w*w;
        acc[4] += x1.x*w; acc[5] += x1.y*w; acc[6] += x1.z*w; acc[7] += x1.w*w;
    }
    #pragma unroll
    for (int b = 0; b < 8; ++b) po[((size_t)cb*8 + b)*HID_ + n] = acc[b];
}

// ---------------- K4: lm_head partials (inline residual + po combine) ----------------
__global__ __launch_bounds__(256) void k_lm_part(const int* __restrict__ tokens,
        const float* __restrict__ embed, const float* __restrict__ po,
        const float* __restrict__ Wlm, float* __restrict__ plm) {
    __shared__ float xs[CK_LM * 8];         // [kk][b]
    const int c  = blockIdx.y;
    const int k0 = c * CK_LM;
    const int t  = threadIdx.x;
    {   // stage y[b][k0..k0+128) = embed + sum of 32 po partials
        int bb = t >> 5, j = t & 31;        // j: float4 within 128 cols
        size_t col4 = (size_t)(k0 >> 2) + j;
        float4 a = ((const float4*)embed)[(size_t)tokens[bb]*(HID_/4) + col4];
        for (int c2 = 0; c2 < KSP_O; ++c2) {
            float4 p = ((const float4*)po)[(size_t)(c2*8 + bb)*(HID_/4) + col4];
            a.x += p.x; a.y += p.y; a.z += p.z; a.w += p.w;
        }
        xs[(j*4+0)*8 + bb] = a.x;
        xs[(j*4+1)*8 + bb] = a.y;
        xs[(j*4+2)*8 + bb] = a.z;
        xs[(j*4+3)*8 + bb] = a.w;
    }
    __syncthreads();

    const int n0 = blockIdx.x * 1024 + t * 4;
    if (n0 >= VOCAB_) return;
    float4 acc[8];
    #pragma unroll
    for (int b = 0; b < 8; ++b) acc[b] = make_float4(0.f,0.f,0.f,0.f);
    const float* wp = Wlm + (size_t)k0 * VOCAB_ + n0;
    #pragma unroll 4
    for (int kk = 0; kk < CK_LM; ++kk) {
        float4 w = *(const float4*)wp; wp += VOCAB_;
        float4 x0 = *(const float4*)&xs[kk*8];
        float4 x1 = *(const float4*)&xs[kk*8 + 4];
        acc[0].x += x0.x*w.x; acc[0].y += x0.x*w.y; acc[0].z += x0.x*w.z; acc[0].w += x0.x*w.w;
        acc[1].x += x0.y*w.x; acc[1].y += x0.y*w.y; acc[1].z += x0.y*w.z; acc[1].w += x0.y*w.w;
        acc[2].x += x0.z*w.x; acc[2].y += x0.z*w.y; acc[2].z += x0.z*w.z; acc[2].w += x0.z*w.w;
        acc[3].x += x0.w*w.x; acc[3].y += x0.w*w.y; acc[3].z += x0.w*w.z; acc[3].w += x0.w*w.w;
        acc[4].x += x1.x*w.x; acc[4].y += x1.x*w.y; acc[4].z += x1.x*w.z; acc[4].w += x1.x*w.w;
        acc[5].x += x1.y*w.x; acc[5].y += x1.y*w.y; acc[5].z += x1.y*w.z; acc[5].w += x1.y*w.w;
        acc[6].x += x1.z*w.x; acc[6].y += x1.z*w.y; acc[6].z += x1.z*w.z; acc[6].w += x1.z*w.w;
        acc[7].x += x1.w*w.x; acc[7].y += x1.w*w.y; acc[7].z += x1.w*w.z; acc[7].w += x1.w*w.w;
    }
    #pragma unroll
    for (int b = 0; b < 8; ++b)
        *(float4*)&plm[(size_t)(c*8 + b)*VOCAB_ + n0] = acc[b];
}

// ---------------- K5: lm_head combine -> logits ----------------
__global__ __launch_bounds__(256) void k_lm_comb(const float* __restrict__ plm,
                                                 float* __restrict__ out) {
    const int b = blockIdx.y;
    const int n4 = blockIdx.x * 256 + threadIdx.x;
    if (n4 >= VOCAB_/4) return;
    float4 s = make_float4(0.f,0.f,0.f,0.f);
    #pragma unroll
    for (int c = 0; c < KSP_LM; ++c) {
        float4 p = ((const float4*)plm)[(size_t)(c*8 + b)*(VOCAB_/4) + n4];
        s.x += p.x; s.y += p.y; s.z += p.z; s.w += p.w;
    }
    ((float4*)out)[(size_t)b*(VOCAB_/4) + n4] = s;
}

extern "C" void kernel_launch(void* const* d_in, const int* in_sizes, int n_in,
                              void* d_out, int out_size, void* d_ws, size_t ws_size,
                              hipStream_t stream) {
    const int*   tokens    = (const int*)  d_in[0];
    const int*   positions = (const int*)  d_in[1];
    const int*   btab      = (const int*)  d_in[2];
    const float* kc        = (const float*)d_in[3];
    const float* vc        = (const float*)d_in[4];
    const float* embed     = (const float*)d_in[5];
    const float* Wq        = (const float*)d_in[6];
    const float* Wk        = (const float*)d_in[7];
    const float* Wv        = (const float*)d_in[8];
    const float* Wo        = (const float*)d_in[9];
    const float* Wlm       = (const float*)d_in[10];
    float* out = (float*)d_out;
    float* ws  = (float*)d_ws;

    float* pqkv = ws + OFF_PQKV;
    float* pm   = ws + OFF_PM;
    float* pl   = ws + OFF_PL;
    float* pacc = ws + OFF_PACC;
    float* po   = ws + OFF_PO;
    float* plm  = ws + OFF_PLM;

    k_qkv_part<<<dim3(NCOL_QKV/256, KSP_QKV), 256, 0, stream>>>(tokens, embed, Wq, Wk, Wv, pqkv);
    k_attn    <<<dim3(NCHUNK, HKV_, B_), 256, 0, stream>>>(pqkv, kc, vc, positions, btab,
                                                           pm, pl, pacc);
    k_o_part  <<<dim3(HID_/256, KSP_O), 256, 0, stream>>>(pm, pl, pacc, Wo, po);
    k_lm_part <<<dim3((VOCAB_ + 1023)/1024, KSP_LM), 256, 0, stream>>>(tokens, embed, po, Wlm, plm);
    k_lm_comb <<<dim3((VOCAB_/4 + 255)/256, B_), 256, 0, stream>>>(plm, out);
}

// Round 4
// 115.462 us; speedup vs baseline: 1.9717x; 1.0889x over previous
//
#include <hip/hip_runtime.h>
#include <cstdint>
#include <cstddef>

// ---- problem constants ----
constexpr int B_    = 8;
constexpr int HKV_  = 8;
constexpr int G_    = 2;      // query heads per kv head
constexpr int D_    = 128;
constexpr int HID_  = 2048;
constexpr int VOCAB_= 32000;
constexpr int BS_   = 16;
constexpr int MAXB_ = 256;
constexpr int L_    = 4096;

// ---- tiling ----
constexpr int KSP_QKV = 32;  constexpr int CK_QKV = HID_ / KSP_QKV;  // 64
constexpr int KSP_O   = 32;                                          // 64 K-rows each
constexpr int KSP_LM  = 16;  constexpr int CK_LM  = HID_ / KSP_LM;   // 128
constexpr int CHUNK   = 128; constexpr int NCHUNK = L_ / CHUNK;      // 32
constexpr int NCOL_QKV = HID_ + 1024 + 1024;                         // 4096

// ---- workspace layout (floats) ----
constexpr size_t OFF_PQKV = 0;                                         // 32*8*4096
constexpr size_t OFF_PM   = OFF_PQKV + (size_t)KSP_QKV*B_*NCOL_QKV;
constexpr size_t OFF_PL   = OFF_PM   + (size_t)B_*HKV_*NCHUNK*G_;
constexpr size_t OFF_PACC = OFF_PL   + (size_t)B_*HKV_*NCHUNK*G_;
constexpr size_t OFF_PO   = OFF_PACC + (size_t)B_*HKV_*NCHUNK*G_*D_;
constexpr size_t OFF_PLM  = OFF_PO   + (size_t)KSP_O*B_*HID_;
// end = OFF_PLM + 16*8*32000 ~= 6.2M floats ~= 25 MB

// ---- nontemporal load helpers (streamed-once operands: weights, KV cache) ----
typedef float f32x4_t __attribute__((ext_vector_type(4)));
__device__ __forceinline__ float4 ntload4(const float* p) {
    f32x4_t v = __builtin_nontemporal_load((const f32x4_t*)p);
    return make_float4(v.x, v.y, v.z, v.w);
}
__device__ __forceinline__ float ntload1(const float* p) {
    return __builtin_nontemporal_load(p);
}

// ---------------- K1: fused q/k/v projection partials ----------------
__global__ __launch_bounds__(256) void k_qkv_part(const int* __restrict__ tokens,
        const float* __restrict__ embed,
        const float* __restrict__ Wq, const float* __restrict__ Wk,
        const float* __restrict__ Wv, float* __restrict__ pout) {
    __shared__ float xs[CK_QKV * 8];           // [kk][b]
    const int c  = blockIdx.y;
    const int k0 = c * CK_QKV;
    const int n  = blockIdx.x * 256 + threadIdx.x;   // 0..4095
    for (int idx = threadIdx.x; idx < CK_QKV*8; idx += 256) {
        int b = idx >> 6, kk = idx & (CK_QKV-1);
        xs[kk*8 + b] = embed[(size_t)tokens[b]*HID_ + k0 + kk];
    }
    const float* Wp; int stride, col;
    if (n < HID_)            { Wp = Wq; stride = HID_; col = n; }
    else if (n < HID_+1024)  { Wp = Wk; stride = 1024; col = n - HID_; }
    else                     { Wp = Wv; stride = 1024; col = n - HID_ - 1024; }
    __syncthreads();
    float acc[8] = {0,0,0,0,0,0,0,0};
    const float* wp = Wp + (size_t)k0 * stride + col;
    #pragma unroll 16
    for (int kk = 0; kk < CK_QKV; ++kk) {
        float w = ntload1(wp); wp += stride;
        float4 x0 = *(const float4*)&xs[kk*8];
        float4 x1 = *(const float4*)&xs[kk*8 + 4];
        acc[0] += x0.x*w; acc[1] += x0.y*w; acc[2] += x0.z*w; acc[3] += x0.w*w;
        acc[4] += x1.x*w; acc[5] += x1.y*w; acc[6] += x1.z*w; acc[7] += x1.w*w;
    }
    float* po = pout + (size_t)c * 8 * NCOL_QKV + n;
    #pragma unroll
    for (int b = 0; b < 8; ++b) po[(size_t)b*NCOL_QKV] = acc[b];
}

// ---------------- K2: flash-decode attention (inline qkv combine) ----------------
__global__ __launch_bounds__(256) void k_attn(const float* __restrict__ pqkv,
        const float* __restrict__ kc, const float* __restrict__ vc,
        const int* __restrict__ positions, const int* __restrict__ btab,
        float* __restrict__ pm, float* __restrict__ pl, float* __restrict__ pacc) {
    const int ch = blockIdx.x, hkv = blockIdx.y, b = blockIdx.z;
    const int pos = positions[b];
    const int c0  = ch * CHUNK;
    const size_t pbase = (size_t)(b*HKV_ + hkv)*NCHUNK + ch;
    const int t = threadIdx.x;
    if (c0 > pos) {
        if (t < 2) { pm[pbase*2 + t] = -1e30f; pl[pbase*2 + t] = 0.f; }
        pacc[pbase*256 + t] = 0.f;
        return;
    }
    const bool haspos = (pos < c0 + CHUNK);   // c0 <= pos already

    __shared__ float qs[2*D_];      // combined+scaled q, [g][d]
    __shared__ float knvs[2*D_];    // combined kn|vn row for l==pos
    __shared__ int   bts[CHUNK/BS_];
    __shared__ float acc_l[8][256];
    __shared__ float ml_l[8][2][2];

    const float4* pq4 = (const float4*)pqkv;
    const float scale = 0.08838834764831845f;   // 1/sqrt(128)
    if (t < 64) {                   // q combine: 64 float4 = 256 floats
        float4 s = make_float4(0.f,0.f,0.f,0.f);
        size_t cb4 = (size_t)hkv*64 + t;        // (hkv*256)/4 + t
        for (int cc = 0; cc < KSP_QKV; ++cc) {
            float4 p = pq4[(size_t)(cc*8 + b)*(NCOL_QKV/4) + cb4];
            s.x += p.x; s.y += p.y; s.z += p.z; s.w += p.w;
        }
        s.x *= scale; s.y *= scale; s.z *= scale; s.w *= scale;
        ((float4*)qs)[t] = s;
    } else if (t < 128 && haspos) { // kn|vn combine: 64 float4
        int j = t - 64;
        size_t cb4 = (j < 32) ? (size_t)(HID_ + hkv*D_)/4 + j
                              : (size_t)(HID_ + 1024 + hkv*D_)/4 + (j - 32);
        float4 s = make_float4(0.f,0.f,0.f,0.f);
        for (int cc = 0; cc < KSP_QKV; ++cc) {
            float4 p = pq4[(size_t)(cc*8 + b)*(NCOL_QKV/4) + cb4];
            s.x += p.x; s.y += p.y; s.z += p.z; s.w += p.w;
        }
        ((float4*)knvs)[j] = s;
    }
    if (t < CHUNK/BS_) bts[t] = btab[b*MAXB_ + ch*(CHUNK/BS_) + t];
    __syncthreads();

    const int hw = t >> 5, l32 = t & 31;
    float4 q0 = ((const float4*)qs)[l32];
    float4 q1 = ((const float4*)qs)[32 + l32];

    float m0 = -1e30f, m1 = -1e30f, l0 = 0.f, l1 = 0.f;
    float a0[4] = {0,0,0,0}, a1[4] = {0,0,0,0};

    #pragma unroll 8
    for (int i = 0; i < CHUNK/8; ++i) {
        const int lo = i*8 + hw;                 // offset in chunk, uniform per half-wave
        const int l  = c0 + lo;
        const bool valid = (l < pos);            // l==pos handled separately
        size_t row = (size_t)bts[lo >> 4] * BS_ + (lo & (BS_-1));
        size_t off = (row*HKV_ + hkv)*D_ + l32*4;
        float4 kv = ntload4(kc + off);
        float4 vv = ntload4(vc + off);
        float s0 = q0.x*kv.x + q0.y*kv.y + q0.z*kv.z + q0.w*kv.w;
        float s1 = q1.x*kv.x + q1.y*kv.y + q1.z*kv.z + q1.w*kv.w;
        #pragma unroll
        for (int m = 16; m >= 1; m >>= 1) { s0 += __shfl_xor(s0, m); s1 += __shfl_xor(s1, m); }
        if (!valid) { s0 = -1e30f; s1 = -1e30f; }
        float nm0 = fmaxf(m0, s0);
        float cr0 = __expf(m0 - nm0);
        float p0  = valid ? __expf(s0 - nm0) : 0.f;
        m0 = nm0; l0 = l0*cr0 + p0;
        a0[0] = a0[0]*cr0 + p0*vv.x; a0[1] = a0[1]*cr0 + p0*vv.y;
        a0[2] = a0[2]*cr0 + p0*vv.z; a0[3] = a0[3]*cr0 + p0*vv.w;
        float nm1 = fmaxf(m1, s1);
        float cr1 = __expf(m1 - nm1);
        float p1  = valid ? __expf(s1 - nm1) : 0.f;
        m1 = nm1; l1 = l1*cr1 + p1;
        a1[0] = a1[0]*cr1 + p1*vv.x; a1[1] = a1[1]*cr1 + p1*vv.y;
        a1[2] = a1[2]*cr1 + p1*vv.z; a1[3] = a1[3]*cr1 + p1*vv.w;
    }

    // new-token update (cache value at slot is stale; use combined kn/vn)
    if (haspos && hw == 0) {
        float4 kv = ((const float4*)knvs)[l32];
        float4 vv = ((const float4*)knvs)[32 + l32];
        float s0 = q0.x*kv.x + q0.y*kv.y + q0.z*kv.z + q0.w*kv.w;
        float s1 = q1.x*kv.x + q1.y*kv.y + q1.z*kv.z + q1.w*kv.w;
        #pragma unroll
        for (int m = 16; m >= 1; m >>= 1) { s0 += __shfl_xor(s0, m); s1 += __shfl_xor(s1, m); }
        float nm0 = fmaxf(m0, s0);
        float cr0 = __expf(m0 - nm0);
        float p0  = __expf(s0 - nm0);
        m0 = nm0; l0 = l0*cr0 + p0;
        a0[0] = a0[0]*cr0 + p0*vv.x; a0[1] = a0[1]*cr0 + p0*vv.y;
        a0[2] = a0[2]*cr0 + p0*vv.z; a0[3] = a0[3]*cr0 + p0*vv.w;
        float nm1 = fmaxf(m1, s1);
        float cr1 = __expf(m1 - nm1);
        float p1  = __expf(s1 - nm1);
        m1 = nm1; l1 = l1*cr1 + p1;
        a1[0] = a1[0]*cr1 + p1*vv.x; a1[1] = a1[1]*cr1 + p1*vv.y;
        a1[2] = a1[2]*cr1 + p1*vv.z; a1[3] = a1[3]*cr1 + p1*vv.w;
    }

    *(float4*)&acc_l[hw][0*D_ + l32*4] = make_float4(a0[0],a0[1],a0[2],a0[3]);
    *(float4*)&acc_l[hw][1*D_ + l32*4] = make_float4(a1[0],a1[1],a1[2],a1[3]);
    if (l32 == 0) {
        ml_l[hw][0][0] = m0; ml_l[hw][0][1] = l0;
        ml_l[hw][1][0] = m1; ml_l[hw][1][1] = l1;
    }
    __syncthreads();

    const int g = t >> 7, d = t & 127;
    float M = -1e30f;
    #pragma unroll
    for (int h = 0; h < 8; ++h) M = fmaxf(M, ml_l[h][g][0]);
    float Ls = 0.f, val = 0.f;
    #pragma unroll
    for (int h = 0; h < 8; ++h) {
        float w = __expf(ml_l[h][g][0] - M);
        Ls  += w * ml_l[h][g][1];
        val += w * acc_l[h][g*D_ + d];
    }
    pacc[pbase*256 + t] = val;
    if (d == 0) { pm[pbase*2 + g] = M; pl[pbase*2 + g] = Ls; }
}

// ---------------- K3: o_proj partials (inline attention combine) ----------------
__global__ __launch_bounds__(256) void k_o_part(const float* __restrict__ pm,
        const float* __restrict__ pl, const float* __restrict__ pacc,
        const float* __restrict__ Wo, float* __restrict__ po) {
    const int cb   = blockIdx.y;            // 0..31
    const int head = cb >> 1;               // query head 0..15
    const int hkv  = head >> 1, g = head & 1;
    const int dhalf = (cb & 1) * 64;        // which 64 dims of the head
    const int t = threadIdx.x;
    const int n = blockIdx.x * 256 + t;     // 0..2047

    __shared__ float pms[8][NCHUNK], pls[8][NCHUNK];
    __shared__ float wch[8][NCHUNK];
    __shared__ float wsum[8];
    __shared__ float xs[64 * 8];            // [kk][b]

    {   // load pm/pl for all (b, ch)
        int bb = t >> 5, ch = t & 31;
        size_t ix = ((size_t)(bb*HKV_ + hkv)*NCHUNK + ch)*2 + g;
        pms[bb][ch] = pm[ix];
        pls[bb][ch] = pl[ix];
    }
    __syncthreads();
    if (t < 8) {
        float M = -1e30f;
        for (int ch = 0; ch < NCHUNK; ++ch) M = fmaxf(M, pms[t][ch]);
        float Ls = 0.f;
        for (int ch = 0; ch < NCHUNK; ++ch) {
            float w = __expf(pms[t][ch] - M);
            wch[t][ch] = w;
            Ls += w * pls[t][ch];
        }
        wsum[t] = 1.f / Ls;
    }
    __syncthreads();
    if (t < 128) {      // stage attn-out slice [8 b][64 d] via float4
        int bb = t >> 4, j = t & 15;
        float4 a = make_float4(0.f,0.f,0.f,0.f);
        size_t base4 = ((size_t)(bb*HKV_ + hkv)*NCHUNK)*64 + (size_t)(g*128 + dhalf)/4 + j;
        for (int ch = 0; ch < NCHUNK; ++ch) {
            float w = wch[bb][ch];
            float4 p = ((const float4*)pacc)[base4 + (size_t)ch*64];
            a.x += w*p.x; a.y += w*p.y; a.z += w*p.z; a.w += w*p.w;
        }
        float inv = wsum[bb];
        xs[(j*4+0)*8 + bb] = a.x*inv;
        xs[(j*4+1)*8 + bb] = a.y*inv;
        xs[(j*4+2)*8 + bb] = a.z*inv;
        xs[(j*4+3)*8 + bb] = a.w*inv;
    }
    __syncthreads();

    float acc[8] = {0,0,0,0,0,0,0,0};
    const float* wp = Wo + (size_t)(head*D_ + dhalf) * HID_ + n;
    #pragma unroll 16
    for (int kk = 0; kk < 64; ++kk) {
        float w = ntload1(wp); wp += HID_;
        float4 x0 = *(const float4*)&xs[kk*8];
        float4 x1 = *(const float4*)&xs[kk*8 + 4];
        acc[0] += x0.x*w; acc[1] += x0.y*w; acc[2] += x0.z*w; acc[3] += x0.w*w;
        acc[4] += x1.x*w; acc[5] += x1.y*w; acc[6] += x1.z*w; acc[7] += x1.w*w;
    }
    #pragma unroll
    for (int b = 0; b < 8; ++b) po[((size_t)cb*8 + b)*HID_ + n] = acc[b];
}

// ---------------- K4: lm_head partials (inline residual + po combine) ----------------
__global__ __launch_bounds__(256) void k_lm_part(const int* __restrict__ tokens,
        const float* __restrict__ embed, const float* __restrict__ po,
        const float* __restrict__ Wlm, float* __restrict__ plm) {
    __shared__ float xs[CK_LM * 8];         // [kk][b]
    const int c  = blockIdx.y;
    const int k0 = c * CK_LM;
    const int t  = threadIdx.x;
    {   // stage y[b][k0..k0+128) = embed + sum of 32 po partials
        int bb = t >> 5, j = t & 31;        // j: float4 within 128 cols
        size_t col4 = (size_t)(k0 >> 2) + j;
        float4 a = ((const float4*)embed)[(size_t)tokens[bb]*(HID_/4) + col4];
        for (int c2 = 0; c2 < KSP_O; ++c2) {
            float4 p = ((const float4*)po)[(size_t)(c2*8 + bb)*(HID_/4) + col4];
            a.x += p.x; a.y += p.y; a.z += p.z; a.w += p.w;
        }
        xs[(j*4+0)*8 + bb] = a.x;
        xs[(j*4+1)*8 + bb] = a.y;
        xs[(j*4+2)*8 + bb] = a.z;
        xs[(j*4+3)*8 + bb] = a.w;
    }
    __syncthreads();

    const int n0 = blockIdx.x * 1024 + t * 4;
    if (n0 >= VOCAB_) return;
    float4 acc[8];
    #pragma unroll
    for (int b = 0; b < 8; ++b) acc[b] = make_float4(0.f,0.f,0.f,0.f);
    const float* wp = Wlm + (size_t)k0 * VOCAB_ + n0;
    #pragma unroll 8
    for (int kk = 0; kk < CK_LM; ++kk) {
        float4 w = ntload4(wp); wp += VOCAB_;
        float4 x0 = *(const float4*)&xs[kk*8];
        float4 x1 = *(const float4*)&xs[kk*8 + 4];
        acc[0].x += x0.x*w.x; acc[0].y += x0.x*w.y; acc[0].z += x0.x*w.z; acc[0].w += x0.x*w.w;
        acc[1].x += x0.y*w.x; acc[1].y += x0.y*w.y; acc[1].z += x0.y*w.z; acc[1].w += x0.y*w.w;
        acc[2].x += x0.z*w.x; acc[2].y += x0.z*w.y; acc[2].z += x0.z*w.z; acc[2].w += x0.z*w.w;
        acc[3].x += x0.w*w.x; acc[3].y += x0.w*w.y; acc[3].z += x0.w*w.z; acc[3].w += x0.w*w.w;
        acc[4].x += x1.x*w.x; acc[4].y += x1.x*w.y; acc[4].z += x1.x*w.z; acc[4].w += x1.x*w.w;
        acc[5].x += x1.y*w.x; acc[5].y += x1.y*w.y; acc[5].z += x1.y*w.z; acc[5].w += x1.y*w.w;
        acc[6].x += x1.z*w.x; acc[6].y += x1.z*w.y; acc[6].z += x1.z*w.z; acc[6].w += x1.z*w.w;
        acc[7].x += x1.w*w.x; acc[7].y += x1.w*w.y; acc[7].z += x1.w*w.z; acc[7].w += x1.w*w.w;
    }
    #pragma unroll
    for (int b = 0; b < 8; ++b)
        *(float4*)&plm[(size_t)(c*8 + b)*VOCAB_ + n0] = acc[b];
}

// ---------------- K5: lm_head combine -> logits ----------------
__global__ __launch_bounds__(256) void k_lm_comb(const float* __restrict__ plm,
                                                 float* __restrict__ out) {
    const int b = blockIdx.y;
    const int n4 = blockIdx.x * 256 + threadIdx.x;
    if (n4 >= VOCAB_/4) return;
    float4 s = make_float4(0.f,0.f,0.f,0.f);
    #pragma unroll
    for (int c = 0; c < KSP_LM; ++c) {
        float4 p = ((const float4*)plm)[(size_t)(c*8 + b)*(VOCAB_/4) + n4];
        s.x += p.x; s.y += p.y; s.z += p.z; s.w += p.w;
    }
    ((float4*)out)[(size_t)b*(VOCAB_/4) + n4] = s;
}

extern "C" void kernel_launch(void* const* d_in, const int* in_sizes, int n_in,
                              void* d_out, int out_size, void* d_ws, size_t ws_size,
                              hipStream_t stream) {
    const int*   tokens    = (const int*)  d_in[0];
    const int*   positions = (const int*)  d_in[1];
    const int*   btab      = (const int*)  d_in[2];
    const float* kc        = (const float*)d_in[3];
    const float* vc        = (const float*)d_in[4];
    const float* embed     = (const float*)d_in[5];
    const float* Wq        = (const float*)d_in[6];
    const float* Wk        = (const float*)d_in[7];
    const float* Wv        = (const float*)d_in[8];
    const float* Wo        = (const float*)d_in[9];
    const float* Wlm       = (const float*)d_in[10];
    float* out = (float*)d_out;
    float* ws  = (float*)d_ws;

    float* pqkv = ws + OFF_PQKV;
    float* pm   = ws + OFF_PM;
    float* pl   = ws + OFF_PL;
    float* pacc = ws + OFF_PACC;
    float* po   = ws + OFF_PO;
    float* plm  = ws + OFF_PLM;

    k_qkv_part<<<dim3(NCOL_QKV/256, KSP_QKV), 256, 0, stream>>>(tokens, embed, Wq, Wk, Wv, pqkv);
    k_attn    <<<dim3(NCHUNK, HKV_, B_), 256, 0, stream>>>(pqkv, kc, vc, positions, btab,
                                                           pm, pl, pacc);
    k_o_part  <<<dim3(HID_/256, KSP_O), 256, 0, stream>>>(pm, pl, pacc, Wo, po);
    k_lm_part <<<dim3((VOCAB_ + 1023)/1024, KSP_LM), 256, 0, stream>>>(tokens, embed, po, Wlm, plm);
    k_lm_comb <<<dim3((VOCAB_/4 + 255)/256, B_), 256, 0, stream>>>(plm, out);
}